// Round 1
// baseline (1539.680 us; speedup 1.0000x reference)
//
#include <hip/hip_runtime.h>
#include <math.h>

// Problem constants (C, HID, etc. are structural; N and E taken from in_sizes)
#define CDIM 64
#define NBES 8

#define SQRT3_F     1.7320508075688772f
#define INV_SQRT3_F 0.57735026918962576f
#define INV_SQRT2_F 0.70710678118654752f
#define INV_AVG_NN  0.0625f

// ---------------------------------------------------------------------------
// h0 init: h0[n,k] = node_embed_W[species[n], k]
__global__ __launch_bounds__(256) void k_init(float* __restrict__ h0,
                                              const int* __restrict__ species,
                                              const float* __restrict__ embedW,
                                              int nnodes) {
    int idx = blockIdx.x * 256 + threadIdx.x;
    if (idx < nnodes * 64) {
        int n = idx >> 6, k = idx & 63;
        h0[idx] = embedW[species[n] * 64 + k];
    }
}

// ---------------------------------------------------------------------------
// lin_up: x0 = h0 @ W0 ; x1[d] = h1[d] @ W1   (h1 stored [N][3][C])
__global__ __launch_bounds__(256) void k_linup(const float* __restrict__ h0,
                                               const float* __restrict__ h1,
                                               const float* __restrict__ W0,
                                               const float* __restrict__ W1,
                                               float* __restrict__ x0,
                                               float* __restrict__ x1,
                                               int nnodes) {
    __shared__ float sh[4][4][64];
    const int w = threadIdx.x >> 6, k = threadIdx.x & 63;
    const int n = blockIdx.x * 4 + w;
    const bool valid = n < nnodes;
    float v0 = valid ? h0[n * 64 + k] : 0.f;
    float v1 = valid ? h1[n * 192 + k] : 0.f;
    float v2 = valid ? h1[n * 192 + 64 + k] : 0.f;
    float v3 = valid ? h1[n * 192 + 128 + k] : 0.f;
    sh[w][0][k] = v0; sh[w][1][k] = v1; sh[w][2][k] = v2; sh[w][3][k] = v3;
    __syncthreads();
    float a0 = 0.f, a1 = 0.f, a2 = 0.f, a3 = 0.f;
    for (int c = 0; c < 64; ++c) {
        float w0 = W0[c * 64 + k], w1 = W1[c * 64 + k];
        a0 = fmaf(sh[w][0][c], w0, a0);
        a1 = fmaf(sh[w][1][c], w1, a1);
        a2 = fmaf(sh[w][2][c], w1, a2);
        a3 = fmaf(sh[w][3][c], w1, a3);
    }
    if (valid) {
        x0[n * 64 + k] = a0;
        x1[n * 192 + k] = a1;
        x1[n * 192 + 64 + k] = a2;
        x1[n * 192 + 128 + k] = a3;
    }
}

// ---------------------------------------------------------------------------
// Edge kernel: 64 edges per 320-thread block.
// Phases: geometry+bessel -> hid1 -> hid2 -> (per p,c) tpw -> messages -> atomics
__global__ __launch_bounds__(320, 4) void k_edge(
    const float* __restrict__ pos, const int* __restrict__ eidx,
    const float* __restrict__ x0, const float* __restrict__ x1,
    const float* __restrict__ W1, const float* __restrict__ W2,
    const float* __restrict__ W3,
    float* __restrict__ M0, float* __restrict__ M1, int nedges) {
    __shared__ __align__(16) float sFEAT[64][8];
    __shared__ float sY1[64][3];
    __shared__ int sSend[64];
    __shared__ int sRecv[64];
    __shared__ __align__(16) float sH1[64][64];
    __shared__ __align__(16) float sH2[64][64];
    __shared__ float sTPW[8 * 320];

    const int t = threadIdx.x;

    // ---- P0: geometry + radial features (fp64 for accuracy), threads 0..63
    if (t < 64) {
        int e = blockIdx.x * 64 + t;
        int s = 0, r = 0;
        float y0 = 0.f, y1 = 0.f, y2 = 0.f;
        float feats[NBES];
#pragma unroll
        for (int b = 0; b < NBES; ++b) feats[b] = 0.f;
        if (e < nedges) {
            s = eidx[e];
            r = eidx[nedges + e];
            double dx = (double)pos[3 * s + 0] - (double)pos[3 * r + 0];
            double dy = (double)pos[3 * s + 1] - (double)pos[3 * r + 1];
            double dz = (double)pos[3 * s + 2] - (double)pos[3 * r + 2];
            double rr = sqrt(dx * dx + dy * dy + dz * dz);
            if (rr < 1e-6) rr = 1e-6;
            double inv = 1.0 / rr;
            y0 = (float)(1.7320508075688772 * dx * inv);
            y1 = (float)(1.7320508075688772 * dy * inv);
            y2 = (float)(1.7320508075688772 * dz * inv);
            double xx = rr * 0.2;  // r / R_MAX
            double f = 0.0;
            if (xx < 1.0) {
                double x2 = xx * xx, x3 = x2 * xx, x6 = x3 * x3;
                f = 1.0 - 28.0 * x6 + 48.0 * x6 * xx - 21.0 * x6 * x2;
            }
            double pref = 0.63245553203367587 * f * inv;  // sqrt(2/R_MAX)
#pragma unroll
            for (int b = 0; b < NBES; ++b) {
                double arg = (double)(b + 1) * 3.14159265358979324 * rr * 0.2;
                feats[b] = (float)(sin(arg) * pref);
            }
        }
        sSend[t] = s;
        sRecv[t] = r;
        sY1[t][0] = y0; sY1[t][1] = y1; sY1[t][2] = y2;
#pragma unroll
        for (int b = 0; b < NBES; ++b) sFEAT[t][b] = feats[b];
    }
    __syncthreads();

    // ---- P1: hid1 = silu(feat @ W1), threads 0..255 (wave w -> 16 edges)
    if (t < 256) {
        const int wv = t >> 6, j = t & 63;
        float w1c[NBES];
#pragma unroll
        for (int b = 0; b < NBES; ++b) w1c[b] = W1[b * 64 + j];
#pragma unroll
        for (int i = 0; i < 16; ++i) {
            int el = wv * 16 + i;
            float acc = 0.f;
#pragma unroll
            for (int b = 0; b < NBES; ++b) acc = fmaf(sFEAT[el][b], w1c[b], acc);
            sH1[el][j] = acc / (1.0f + expf(-acc));
        }
    }
    __syncthreads();

    // ---- P2: hid2 = silu(hid1 @ W2)
    if (t < 256) {
        const int wv = t >> 6, j = t & 63;
        float w2c[64];
#pragma unroll
        for (int c = 0; c < 64; ++c) w2c[c] = W2[c * 64 + j];
#pragma unroll
        for (int i = 0; i < 16; ++i) {
            int el = wv * 16 + i;
            const float4* row = (const float4*)(&sH1[el][0]);
            float acc = 0.f;
#pragma unroll
            for (int c4 = 0; c4 < 16; ++c4) {
                float4 v = row[c4];
                acc = fmaf(v.x, w2c[4 * c4 + 0], acc);
                acc = fmaf(v.y, w2c[4 * c4 + 1], acc);
                acc = fmaf(v.z, w2c[4 * c4 + 2], acc);
                acc = fmaf(v.w, w2c[4 * c4 + 3], acc);
            }
            sH2[el][j] = acc / (1.0f + expf(-acc));
        }
    }

    // ---- P3: each thread owns column (p = t>>6, c = t&63) of W3 in VGPRs.
    // #pragma unroll is ESSENTIAL: without it the array is dynamically
    // indexed -> demoted to scratch (VGPR_Count was 52), and P4's inner
    // matmul becomes a scratch-load latency chain (the prior bottleneck).
    float w3c[64];
#pragma unroll
    for (int h = 0; h < 64; ++h) w3c[h] = W3[h * 320 + t];
    __syncthreads();  // sH2 ready

    // ---- P4: tpw + messages + atomic scatter, 8 edges at a time
    for (int eg = 0; eg < 8; ++eg) {
        float tp[8];
#pragma unroll
        for (int i = 0; i < 8; ++i) {
            int el = eg * 8 + i;
            const float4* row = (const float4*)(&sH2[el][0]);
            float acc = 0.f;
#pragma unroll
            for (int h4 = 0; h4 < 16; ++h4) {
                float4 v = row[h4];
                acc = fmaf(v.x, w3c[4 * h4 + 0], acc);
                acc = fmaf(v.y, w3c[4 * h4 + 1], acc);
                acc = fmaf(v.z, w3c[4 * h4 + 2], acc);
                acc = fmaf(v.w, w3c[4 * h4 + 3], acc);
            }
            tp[i] = acc;
        }
        __syncthreads();  // previous group's sTPW reads complete
#pragma unroll
        for (int i = 0; i < 8; ++i) sTPW[i * 320 + t] = tp[i];
        __syncthreads();  // sTPW ready
        // message phase: 8 edges x 64 channels = 512 items over 320 threads
        for (int v = t; v < 512; v += 320) {
            int i = v >> 6, cc = v & 63;
            int el = eg * 8 + i;
            int s = sSend[el], r = sRecv[el];
            float X0 = x0[s * 64 + cc];
            float Xx = x1[s * 192 + cc];
            float Xy = x1[s * 192 + 64 + cc];
            float Xz = x1[s * 192 + 128 + cc];
            float Yx = sY1[el][0], Yy = sY1[el][1], Yz = sY1[el][2];
            const float* tpr = &sTPW[i * 320 + cc];
            float t0 = tpr[0], t1 = tpr[64], t2 = tpr[128], t3 = tpr[192],
                  t4 = tpr[256];
            float dotp = Xx * Yx + Xy * Yy + Xz * Yz;
            float m0 = t0 * X0 + t3 * (dotp * INV_SQRT3_F);
            float cx = Xy * Yz - Xz * Yy;
            float cy = Xz * Yx - Xx * Yz;
            float cz = Xx * Yy - Xy * Yx;
            float m1x = t1 * X0 * Yx + t2 * Xx + t4 * (cx * INV_SQRT2_F);
            float m1y = t1 * X0 * Yy + t2 * Xy + t4 * (cy * INV_SQRT2_F);
            float m1z = t1 * X0 * Yz + t2 * Xz + t4 * (cz * INV_SQRT2_F);
            atomicAdd(&M0[r * 64 + cc], m0 * INV_AVG_NN);
            atomicAdd(&M1[r * 192 + cc], m1x * INV_AVG_NN);
            atomicAdd(&M1[r * 192 + 64 + cc], m1y * INV_AVG_NN);
            atomicAdd(&M1[r * 192 + 128 + cc], m1z * INV_AVG_NN);
        }
    }
}

// ---------------------------------------------------------------------------
// Node update: h = prod_lin( product_basis( lin(M) ) ), in place over M
__global__ __launch_bounds__(256) void k_node(
    float* __restrict__ h0, float* __restrict__ h1,
    const int* __restrict__ species,
    const float* __restrict__ linW0, const float* __restrict__ linW1,
    const float* __restrict__ prodW0, const float* __restrict__ prodW1,
    const float* __restrict__ plinW0, const float* __restrict__ plinW1,
    int nnodes) {
    __shared__ float sh[4][4][64];
    const int w = threadIdx.x >> 6, k = threadIdx.x & 63;
    const int n = blockIdx.x * 4 + w;
    const bool valid = n < nnodes;
    float v0 = valid ? h0[n * 64 + k] : 0.f;
    float v1 = valid ? h1[n * 192 + k] : 0.f;
    float v2 = valid ? h1[n * 192 + 64 + k] : 0.f;
    float v3 = valid ? h1[n * 192 + 128 + k] : 0.f;
    sh[w][0][k] = v0; sh[w][1][k] = v1; sh[w][2][k] = v2; sh[w][3][k] = v3;
    __syncthreads();
    float a0 = 0.f, a1 = 0.f, a2 = 0.f, a3 = 0.f;
    for (int c = 0; c < 64; ++c) {
        float w0 = linW0[c * 64 + k], w1 = linW1[c * 64 + k];
        a0 = fmaf(sh[w][0][c], w0, a0);
        a1 = fmaf(sh[w][1][c], w1, a1);
        a2 = fmaf(sh[w][2][c], w1, a2);
        a3 = fmaf(sh[w][3][c], w1, a3);
    }
    // product basis (elementwise in channel)
    int sp = valid ? species[n] : 0;
    float p00 = prodW0[sp * 192 + k];
    float p01 = prodW0[sp * 192 + 64 + k];
    float p02 = prodW0[sp * 192 + 128 + k];
    float p10 = prodW1[sp * 128 + k];
    float p11 = prodW1[sp * 128 + 64 + k];
    float nsq = a1 * a1 + a2 * a2 + a3 * a3;
    float b0 = p00 * a0 + p01 * (a0 * a0) + p02 * (nsq * INV_SQRT3_F);
    float b1x = p10 * a1 + p11 * (a0 * a1);
    float b1y = p10 * a2 + p11 * (a0 * a2);
    float b1z = p10 * a3 + p11 * (a0 * a3);
    __syncthreads();
    sh[w][0][k] = b0; sh[w][1][k] = b1x; sh[w][2][k] = b1y; sh[w][3][k] = b1z;
    __syncthreads();
    a0 = a1 = a2 = a3 = 0.f;
    for (int c = 0; c < 64; ++c) {
        float w0 = plinW0[c * 64 + k], w1 = plinW1[c * 64 + k];
        a0 = fmaf(sh[w][0][c], w0, a0);
        a1 = fmaf(sh[w][1][c], w1, a1);
        a2 = fmaf(sh[w][2][c], w1, a2);
        a3 = fmaf(sh[w][3][c], w1, a3);
    }
    if (valid) {
        h0[n * 64 + k] = a0;
        h1[n * 192 + k] = a1;
        h1[n * 192 + 64 + k] = a2;
        h1[n * 192 + 128 + k] = a3;
    }
}

// ---------------------------------------------------------------------------
// Output: [N, C, 4] = concat(h0, h1_x, h1_y, h1_z) along last dim
__global__ __launch_bounds__(256) void k_out(const float* __restrict__ h0,
                                             const float* __restrict__ h1,
                                             float4* __restrict__ out,
                                             int nnodes) {
    int idx = blockIdx.x * 256 + threadIdx.x;
    if (idx < nnodes * 64) {
        int n = idx >> 6, c = idx & 63;
        float4 o;
        o.x = h0[idx];
        o.y = h1[n * 192 + c];
        o.z = h1[n * 192 + 64 + c];
        o.w = h1[n * 192 + 128 + c];
        out[idx] = o;
    }
}

// ---------------------------------------------------------------------------
extern "C" void kernel_launch(void* const* d_in, const int* in_sizes, int n_in,
                              void* d_out, int out_size, void* d_ws,
                              size_t ws_size, hipStream_t stream) {
    const float* positions = (const float*)d_in[0];
    const int* species = (const int*)d_in[1];
    const int* eidx = (const int*)d_in[2];
    const float* embedW = (const float*)d_in[3];
    const float* linupW0 = (const float*)d_in[4];
    const float* linupW1 = (const float*)d_in[5];
    const float* mlpW1 = (const float*)d_in[6];
    const float* mlpW2 = (const float*)d_in[7];
    const float* mlpW3 = (const float*)d_in[8];
    const float* linW0 = (const float*)d_in[9];
    const float* linW1 = (const float*)d_in[10];
    const float* prodW0 = (const float*)d_in[11];
    const float* prodW1 = (const float*)d_in[12];
    const float* plinW0 = (const float*)d_in[13];
    const float* plinW1 = (const float*)d_in[14];

    const int nn = in_sizes[0] / 3;   // 25000
    const int ne = in_sizes[2] / 2;   // 400000

    // workspace layout (floats): h0 | h1 | x0 | x1   (M aliases h: h dead
    // once lin_up produced x; node-update reads M row then overwrites it)
    float* h0 = (float*)d_ws;
    float* h1 = h0 + (size_t)nn * 64;
    float* x0 = h1 + (size_t)nn * 192;
    float* x1 = x0 + (size_t)nn * 64;

    const int gridN64 = (nn * 64 + 255) / 256;
    const int gridNode = (nn + 3) / 4;
    const int gridEdge = (ne + 63) / 64;

    hipMemsetAsync(h1, 0, (size_t)nn * 192 * sizeof(float), stream);
    k_init<<<gridN64, 256, 0, stream>>>(h0, species, embedW, nn);

    for (int l = 0; l < 2; ++l) {
        k_linup<<<gridNode, 256, 0, stream>>>(
            h0, h1, linupW0 + l * 4096, linupW1 + l * 4096, x0, x1, nn);
        // zero the scatter accumulators (alias h0/h1)
        hipMemsetAsync(h0, 0, (size_t)nn * 64 * sizeof(float), stream);
        hipMemsetAsync(h1, 0, (size_t)nn * 192 * sizeof(float), stream);
        k_edge<<<gridEdge, 320, 0, stream>>>(
            positions, eidx, x0, x1, mlpW1 + l * 512, mlpW2 + l * 4096,
            mlpW3 + l * 20480, h0, h1, ne);
        k_node<<<gridNode, 256, 0, stream>>>(
            h0, h1, species, linW0 + l * 4096, linW1 + l * 4096,
            prodW0 + l * 768, prodW1 + l * 512, plinW0 + l * 4096,
            plinW1 + l * 4096, nn);
    }
    k_out<<<gridN64, 256, 0, stream>>>(h0, h1, (float4*)d_out, nn);
}

// Round 2
// 1518.857 us; speedup vs baseline: 1.0137x; 1.0137x over previous
//
#include <hip/hip_runtime.h>
#include <math.h>

// Problem constants (C, HID, etc. are structural; N and E taken from in_sizes)
#define CDIM 64
#define NBES 8

#define SQRT3_F     1.7320508075688772f
#define INV_SQRT3_F 0.57735026918962576f
#define INV_SQRT2_F 0.70710678118654752f
#define INV_AVG_NN  0.0625f

// ---------------------------------------------------------------------------
// h0 init: h0[n,k] = node_embed_W[species[n], k]
__global__ __launch_bounds__(256) void k_init(float* __restrict__ h0,
                                              const int* __restrict__ species,
                                              const float* __restrict__ embedW,
                                              int nnodes) {
    int idx = blockIdx.x * 256 + threadIdx.x;
    if (idx < nnodes * 64) {
        int n = idx >> 6, k = idx & 63;
        h0[idx] = embedW[species[n] * 64 + k];
    }
}

// ---------------------------------------------------------------------------
// lin_up: x0 = h0 @ W0 ; x1[d] = h1[d] @ W1   (h1 stored [N][3][C])
__global__ __launch_bounds__(256) void k_linup(const float* __restrict__ h0,
                                               const float* __restrict__ h1,
                                               const float* __restrict__ W0,
                                               const float* __restrict__ W1,
                                               float* __restrict__ x0,
                                               float* __restrict__ x1,
                                               int nnodes) {
    __shared__ float sh[4][4][64];
    const int w = threadIdx.x >> 6, k = threadIdx.x & 63;
    const int n = blockIdx.x * 4 + w;
    const bool valid = n < nnodes;
    float v0 = valid ? h0[n * 64 + k] : 0.f;
    float v1 = valid ? h1[n * 192 + k] : 0.f;
    float v2 = valid ? h1[n * 192 + 64 + k] : 0.f;
    float v3 = valid ? h1[n * 192 + 128 + k] : 0.f;
    sh[w][0][k] = v0; sh[w][1][k] = v1; sh[w][2][k] = v2; sh[w][3][k] = v3;
    __syncthreads();
    float a0 = 0.f, a1 = 0.f, a2 = 0.f, a3 = 0.f;
    for (int c = 0; c < 64; ++c) {
        float w0 = W0[c * 64 + k], w1 = W1[c * 64 + k];
        a0 = fmaf(sh[w][0][c], w0, a0);
        a1 = fmaf(sh[w][1][c], w1, a1);
        a2 = fmaf(sh[w][2][c], w1, a2);
        a3 = fmaf(sh[w][3][c], w1, a3);
    }
    if (valid) {
        x0[n * 64 + k] = a0;
        x1[n * 192 + k] = a1;
        x1[n * 192 + 64 + k] = a2;
        x1[n * 192 + 128 + k] = a3;
    }
}

// ---------------------------------------------------------------------------
// Edge kernel: 64 edges per 320-thread block.
// Phases: geometry+bessel -> hid1 -> hid2 -> (per p,c) tpw -> messages -> atomics
__global__ __launch_bounds__(320, 3) void k_edge(
    const float* __restrict__ pos, const int* __restrict__ eidx,
    const float* __restrict__ x0, const float* __restrict__ x1,
    const float* __restrict__ W1, const float* __restrict__ W2,
    const float* __restrict__ W3,
    float* __restrict__ M0, float* __restrict__ M1, int nedges) {
    __shared__ __align__(16) float sFEAT[64][8];
    __shared__ float sY1[64][3];
    __shared__ int sSend[64];
    __shared__ int sRecv[64];
    __shared__ __align__(16) float sH1[64][64];
    __shared__ __align__(16) float sH2[64][64];
    __shared__ float sTPW[8 * 320];

    const int t = threadIdx.x;

    // ---- P0: geometry + radial features (fp64 for accuracy), threads 0..63
    if (t < 64) {
        int e = blockIdx.x * 64 + t;
        int s = 0, r = 0;
        float y0 = 0.f, y1 = 0.f, y2 = 0.f;
        float feats[NBES];
#pragma unroll
        for (int b = 0; b < NBES; ++b) feats[b] = 0.f;
        if (e < nedges) {
            s = eidx[e];
            r = eidx[nedges + e];
            double dx = (double)pos[3 * s + 0] - (double)pos[3 * r + 0];
            double dy = (double)pos[3 * s + 1] - (double)pos[3 * r + 1];
            double dz = (double)pos[3 * s + 2] - (double)pos[3 * r + 2];
            double rr = sqrt(dx * dx + dy * dy + dz * dz);
            if (rr < 1e-6) rr = 1e-6;
            double inv = 1.0 / rr;
            y0 = (float)(1.7320508075688772 * dx * inv);
            y1 = (float)(1.7320508075688772 * dy * inv);
            y2 = (float)(1.7320508075688772 * dz * inv);
            double xx = rr * 0.2;  // r / R_MAX
            double f = 0.0;
            if (xx < 1.0) {
                double x2 = xx * xx, x3 = x2 * xx, x6 = x3 * x3;
                f = 1.0 - 28.0 * x6 + 48.0 * x6 * xx - 21.0 * x6 * x2;
            }
            double pref = 0.63245553203367587 * f * inv;  // sqrt(2/R_MAX)
#pragma unroll
            for (int b = 0; b < NBES; ++b) {
                double arg = (double)(b + 1) * 3.14159265358979324 * rr * 0.2;
                feats[b] = (float)(sin(arg) * pref);
            }
        }
        sSend[t] = s;
        sRecv[t] = r;
        sY1[t][0] = y0; sY1[t][1] = y1; sY1[t][2] = y2;
#pragma unroll
        for (int b = 0; b < NBES; ++b) sFEAT[t][b] = feats[b];
    }
    __syncthreads();

    // ---- P1: hid1 = silu(feat @ W1), threads 0..255 (wave w -> 16 edges)
    if (t < 256) {
        const int wv = t >> 6, j = t & 63;
        float w1c[NBES];
#pragma unroll
        for (int b = 0; b < NBES; ++b) w1c[b] = W1[b * 64 + j];
#pragma unroll
        for (int i = 0; i < 16; ++i) {
            int el = wv * 16 + i;
            float acc = 0.f;
#pragma unroll
            for (int b = 0; b < NBES; ++b) acc = fmaf(sFEAT[el][b], w1c[b], acc);
            sH1[el][j] = acc / (1.0f + expf(-acc));
        }
    }
    __syncthreads();

    // ---- P2: hid2 = silu(hid1 @ W2)
    if (t < 256) {
        const int wv = t >> 6, j = t & 63;
        float w2c[64];
#pragma unroll
        for (int c = 0; c < 64; ++c) w2c[c] = W2[c * 64 + j];
#pragma unroll
        for (int i = 0; i < 16; ++i) {
            int el = wv * 16 + i;
            const float4* row = (const float4*)(&sH1[el][0]);
            float acc = 0.f;
#pragma unroll
            for (int c4 = 0; c4 < 16; ++c4) {
                float4 v = row[c4];
                acc = fmaf(v.x, w2c[4 * c4 + 0], acc);
                acc = fmaf(v.y, w2c[4 * c4 + 1], acc);
                acc = fmaf(v.z, w2c[4 * c4 + 2], acc);
                acc = fmaf(v.w, w2c[4 * c4 + 3], acc);
            }
            sH2[el][j] = acc / (1.0f + expf(-acc));
        }
    }

    // ---- P3: each thread owns column (p = t>>6, c = t&63) of W3.
    // VGPR_Count=52 in the last two rounds proves the compiler was
    // REMATERIALIZING these loads at every use (4096 L1/L2 loads per thread
    // in P4 instead of 64). The empty asm with "+v" redefines each value
    // opaquely, so rematerialization is illegal and the column must stay
    // resident in VGPRs. launch_bounds (320,3) gives the allocator a
    // 170-VGPR budget (LDS already limits us to 3 blocks/CU, so no
    // occupancy cost).
    float w3c[64];
#pragma unroll
    for (int h = 0; h < 64; ++h) w3c[h] = W3[h * 320 + t];
#pragma unroll
    for (int h = 0; h < 64; ++h) asm volatile("" : "+v"(w3c[h]));
    __syncthreads();  // sH2 ready

    // ---- P4: tpw + messages + atomic scatter, 8 edges at a time
    for (int eg = 0; eg < 8; ++eg) {
        float tp[8];
#pragma unroll
        for (int i = 0; i < 8; ++i) {
            int el = eg * 8 + i;
            const float4* row = (const float4*)(&sH2[el][0]);
            float acc = 0.f;
#pragma unroll
            for (int h4 = 0; h4 < 16; ++h4) {
                float4 v = row[h4];
                acc = fmaf(v.x, w3c[4 * h4 + 0], acc);
                acc = fmaf(v.y, w3c[4 * h4 + 1], acc);
                acc = fmaf(v.z, w3c[4 * h4 + 2], acc);
                acc = fmaf(v.w, w3c[4 * h4 + 3], acc);
            }
            tp[i] = acc;
        }
        __syncthreads();  // previous group's sTPW reads complete
#pragma unroll
        for (int i = 0; i < 8; ++i) sTPW[i * 320 + t] = tp[i];
        __syncthreads();  // sTPW ready
        // message phase: 8 edges x 64 channels = 512 items over 320 threads
        for (int v = t; v < 512; v += 320) {
            int i = v >> 6, cc = v & 63;
            int el = eg * 8 + i;
            int s = sSend[el], r = sRecv[el];
            float X0 = x0[s * 64 + cc];
            float Xx = x1[s * 192 + cc];
            float Xy = x1[s * 192 + 64 + cc];
            float Xz = x1[s * 192 + 128 + cc];
            float Yx = sY1[el][0], Yy = sY1[el][1], Yz = sY1[el][2];
            const float* tpr = &sTPW[i * 320 + cc];
            float t0 = tpr[0], t1 = tpr[64], t2 = tpr[128], t3 = tpr[192],
                  t4 = tpr[256];
            float dotp = Xx * Yx + Xy * Yy + Xz * Yz;
            float m0 = t0 * X0 + t3 * (dotp * INV_SQRT3_F);
            float cx = Xy * Yz - Xz * Yy;
            float cy = Xz * Yx - Xx * Yz;
            float cz = Xx * Yy - Xy * Yx;
            float m1x = t1 * X0 * Yx + t2 * Xx + t4 * (cx * INV_SQRT2_F);
            float m1y = t1 * X0 * Yy + t2 * Xy + t4 * (cy * INV_SQRT2_F);
            float m1z = t1 * X0 * Yz + t2 * Xz + t4 * (cz * INV_SQRT2_F);
            atomicAdd(&M0[r * 64 + cc], m0 * INV_AVG_NN);
            atomicAdd(&M1[r * 192 + cc], m1x * INV_AVG_NN);
            atomicAdd(&M1[r * 192 + 64 + cc], m1y * INV_AVG_NN);
            atomicAdd(&M1[r * 192 + 128 + cc], m1z * INV_AVG_NN);
        }
    }
}

// ---------------------------------------------------------------------------
// Node update: h = prod_lin( product_basis( lin(M) ) ), in place over M
__global__ __launch_bounds__(256) void k_node(
    float* __restrict__ h0, float* __restrict__ h1,
    const int* __restrict__ species,
    const float* __restrict__ linW0, const float* __restrict__ linW1,
    const float* __restrict__ prodW0, const float* __restrict__ prodW1,
    const float* __restrict__ plinW0, const float* __restrict__ plinW1,
    int nnodes) {
    __shared__ float sh[4][4][64];
    const int w = threadIdx.x >> 6, k = threadIdx.x & 63;
    const int n = blockIdx.x * 4 + w;
    const bool valid = n < nnodes;
    float v0 = valid ? h0[n * 64 + k] : 0.f;
    float v1 = valid ? h1[n * 192 + k] : 0.f;
    float v2 = valid ? h1[n * 192 + 64 + k] : 0.f;
    float v3 = valid ? h1[n * 192 + 128 + k] : 0.f;
    sh[w][0][k] = v0; sh[w][1][k] = v1; sh[w][2][k] = v2; sh[w][3][k] = v3;
    __syncthreads();
    float a0 = 0.f, a1 = 0.f, a2 = 0.f, a3 = 0.f;
    for (int c = 0; c < 64; ++c) {
        float w0 = linW0[c * 64 + k], w1 = linW1[c * 64 + k];
        a0 = fmaf(sh[w][0][c], w0, a0);
        a1 = fmaf(sh[w][1][c], w1, a1);
        a2 = fmaf(sh[w][2][c], w1, a2);
        a3 = fmaf(sh[w][3][c], w1, a3);
    }
    // product basis (elementwise in channel)
    int sp = valid ? species[n] : 0;
    float p00 = prodW0[sp * 192 + k];
    float p01 = prodW0[sp * 192 + 64 + k];
    float p02 = prodW0[sp * 192 + 128 + k];
    float p10 = prodW1[sp * 128 + k];
    float p11 = prodW1[sp * 128 + 64 + k];
    float nsq = a1 * a1 + a2 * a2 + a3 * a3;
    float b0 = p00 * a0 + p01 * (a0 * a0) + p02 * (nsq * INV_SQRT3_F);
    float b1x = p10 * a1 + p11 * (a0 * a1);
    float b1y = p10 * a2 + p11 * (a0 * a2);
    float b1z = p10 * a3 + p11 * (a0 * a3);
    __syncthreads();
    sh[w][0][k] = b0; sh[w][1][k] = b1x; sh[w][2][k] = b1y; sh[w][3][k] = b1z;
    __syncthreads();
    a0 = a1 = a2 = a3 = 0.f;
    for (int c = 0; c < 64; ++c) {
        float w0 = plinW0[c * 64 + k], w1 = plinW1[c * 64 + k];
        a0 = fmaf(sh[w][0][c], w0, a0);
        a1 = fmaf(sh[w][1][c], w1, a1);
        a2 = fmaf(sh[w][2][c], w1, a2);
        a3 = fmaf(sh[w][3][c], w1, a3);
    }
    if (valid) {
        h0[n * 64 + k] = a0;
        h1[n * 192 + k] = a1;
        h1[n * 192 + 64 + k] = a2;
        h1[n * 192 + 128 + k] = a3;
    }
}

// ---------------------------------------------------------------------------
// Output: [N, C, 4] = concat(h0, h1_x, h1_y, h1_z) along last dim
__global__ __launch_bounds__(256) void k_out(const float* __restrict__ h0,
                                             const float* __restrict__ h1,
                                             float4* __restrict__ out,
                                             int nnodes) {
    int idx = blockIdx.x * 256 + threadIdx.x;
    if (idx < nnodes * 64) {
        int n = idx >> 6, c = idx & 63;
        float4 o;
        o.x = h0[idx];
        o.y = h1[n * 192 + c];
        o.z = h1[n * 192 + 64 + c];
        o.w = h1[n * 192 + 128 + c];
        out[idx] = o;
    }
}

// ---------------------------------------------------------------------------
extern "C" void kernel_launch(void* const* d_in, const int* in_sizes, int n_in,
                              void* d_out, int out_size, void* d_ws,
                              size_t ws_size, hipStream_t stream) {
    const float* positions = (const float*)d_in[0];
    const int* species = (const int*)d_in[1];
    const int* eidx = (const int*)d_in[2];
    const float* embedW = (const float*)d_in[3];
    const float* linupW0 = (const float*)d_in[4];
    const float* linupW1 = (const float*)d_in[5];
    const float* mlpW1 = (const float*)d_in[6];
    const float* mlpW2 = (const float*)d_in[7];
    const float* mlpW3 = (const float*)d_in[8];
    const float* linW0 = (const float*)d_in[9];
    const float* linW1 = (const float*)d_in[10];
    const float* prodW0 = (const float*)d_in[11];
    const float* prodW1 = (const float*)d_in[12];
    const float* plinW0 = (const float*)d_in[13];
    const float* plinW1 = (const float*)d_in[14];

    const int nn = in_sizes[0] / 3;   // 25000
    const int ne = in_sizes[2] / 2;   // 400000

    // workspace layout (floats): h0 | h1 | x0 | x1   (M aliases h: h dead
    // once lin_up produced x; node-update reads M row then overwrites it)
    float* h0 = (float*)d_ws;
    float* h1 = h0 + (size_t)nn * 64;
    float* x0 = h1 + (size_t)nn * 192;
    float* x1 = x0 + (size_t)nn * 64;

    const int gridN64 = (nn * 64 + 255) / 256;
    const int gridNode = (nn + 3) / 4;
    const int gridEdge = (ne + 63) / 64;

    hipMemsetAsync(h1, 0, (size_t)nn * 192 * sizeof(float), stream);
    k_init<<<gridN64, 256, 0, stream>>>(h0, species, embedW, nn);

    for (int l = 0; l < 2; ++l) {
        k_linup<<<gridNode, 256, 0, stream>>>(
            h0, h1, linupW0 + l * 4096, linupW1 + l * 4096, x0, x1, nn);
        // zero the scatter accumulators (alias h0/h1)
        hipMemsetAsync(h0, 0, (size_t)nn * 64 * sizeof(float), stream);
        hipMemsetAsync(h1, 0, (size_t)nn * 192 * sizeof(float), stream);
        k_edge<<<gridEdge, 320, 0, stream>>>(
            positions, eidx, x0, x1, mlpW1 + l * 512, mlpW2 + l * 4096,
            mlpW3 + l * 20480, h0, h1, ne);
        k_node<<<gridNode, 256, 0, stream>>>(
            h0, h1, species, linW0 + l * 4096, linW1 + l * 4096,
            prodW0 + l * 768, prodW1 + l * 512, plinW0 + l * 4096,
            plinW1 + l * 4096, nn);
    }
    k_out<<<gridN64, 256, 0, stream>>>(h0, h1, (float4*)d_out, nn);
}